// Round 6
// baseline (1057.971 us; speedup 1.0000x reference)
//
#include <hip/hip_runtime.h>
#include <cmath>

#define NN 50000
#define NE 800000
#define INF_ 128
#define NR 64
#define OF 128
#define SCAN_T 1024

// zero cnt[]; block 0 also computes q3[d] = sum_j W[(256+d),j] * a[j]
__global__ void k_init(const float* __restrict__ W, const float* __restrict__ a,
                       float* __restrict__ q3, int* __restrict__ cnt) {
  int i = blockIdx.x * 256 + threadIdx.x;
  if (i < NN) cnt[i] = 0;
  if (blockIdx.x == 0 && threadIdx.x < NR) {
    const float* row = W + (size_t)(2 * INF_ + threadIdx.x) * OF;
    float acc = 0.f;
    for (int j = 0; j < OF; ++j) acc = fmaf(row[j], a[j], acc);
    q3[threadIdx.x] = acc;
  }
}

// per-node precompute: xW1 = x@W1, xW2 = x@W2, p1 = xW1@a, p2 = xW2@a.
// Fused: src-degree histogram (grid*block == NE exactly, one edge per thread).
__global__ void k_node_pre(const float* __restrict__ x, const float* __restrict__ W,
                           const float* __restrict__ a, const int* __restrict__ ei,
                           float* __restrict__ xW1, float* __restrict__ xW2,
                           float* __restrict__ p1, float* __restrict__ p2,
                           int* __restrict__ cnt) {
  int gid = blockIdx.x * 128 + threadIdx.x;  // 0..799999 == edge id
  atomicAdd(cnt + ei[gid], 1);
  __shared__ float xs[8][INF_];
  __shared__ float red[2][2][8];
  int nb = blockIdx.x * 8;
  int o = threadIdx.x;  // 0..127
  for (int t = 0; t < 8; ++t) xs[t][o] = x[(size_t)(nb + t) * INF_ + o];
  __syncthreads();
  float acc1[8] = {0.f, 0.f, 0.f, 0.f, 0.f, 0.f, 0.f, 0.f};
  float acc2[8] = {0.f, 0.f, 0.f, 0.f, 0.f, 0.f, 0.f, 0.f};
  for (int k = 0; k < INF_; ++k) {
    float w1 = W[(size_t)k * OF + o];
    float w2 = W[(size_t)(INF_ + k) * OF + o];
#pragma unroll
    for (int t = 0; t < 8; ++t) {
      acc1[t] = fmaf(xs[t][k], w1, acc1[t]);
      acc2[t] = fmaf(xs[t][k], w2, acc2[t]);
    }
  }
  float av = a[o];
  int wv = o >> 6, ln = o & 63;
#pragma unroll
  for (int t = 0; t < 8; ++t) {
    xW1[(size_t)(nb + t) * OF + o] = acc1[t];
    xW2[(size_t)(nb + t) * OF + o] = acc2[t];
    float v1 = acc1[t] * av, v2 = acc2[t] * av;
    for (int off = 32; off > 0; off >>= 1) {
      v1 += __shfl_down(v1, off, 64);
      v2 += __shfl_down(v2, off, 64);
    }
    if (ln == 0) { red[0][wv][t] = v1; red[1][wv][t] = v2; }
  }
  __syncthreads();
  if (o < 8) {
    p1[nb + o] = red[0][0][o] + red[0][1][o];
    p2[nb + o] = red[1][0][o] + red[1][1][o];
  }
}

// single-block exclusive scan over cnt -> roff (+cur copy); roff[NN]=NE
__global__ void k_scan(const int* __restrict__ cnt, int* __restrict__ roff,
                       int* __restrict__ cur) {
  __shared__ int part[SCAN_T];
  int t = threadIdx.x;
  const int chunk = (NN + SCAN_T - 1) / SCAN_T;  // 49
  int beg = t * chunk;
  int end = beg + chunk < NN ? beg + chunk : NN;
  int sum = 0;
  for (int i = beg; i < end; ++i) sum += cnt[i];
  part[t] = sum;
  __syncthreads();
  for (int off = 1; off < SCAN_T; off <<= 1) {
    int v = (t >= off) ? part[t - off] : 0;
    __syncthreads();
    part[t] += v;
    __syncthreads();
  }
  int run = (t == 0) ? 0 : part[t - 1];
  for (int i = beg; i < end; ++i) {
    roff[i] = run;
    cur[i] = run;
    run += cnt[i];
  }
  if (t == SCAN_T - 1) roff[NN] = NE;
}

// scatter edge ids + dst into CSR slots (index-only)
__global__ void k_scatter(const int* __restrict__ ei, int* __restrict__ cur,
                          int2* __restrict__ es) {
  int e = blockIdx.x * blockDim.x + threadIdx.x;
  if (e < NE) {
    int pos = atomicAdd(cur + ei[e], 1);
    es[pos] = make_int2(e, ei[NE + e]);
  }
}

// fully fused per-node pass (gather + finalize): one wave per node, single
// nontemporal read of ete. Per edge: logit = p1[n]+p2[dst]+ete[e]·q3
// (64-lane butterfly), ev = exp(leaky_relu(logit)); accumulate ssum, ev*ete,
// ev*xW2[dst] unnormalized. Epilogue: g_row through LDS, g@W3 (W3 is
// L1-resident), + sa*xW1 + normalized o, then ELU — out written exactly once.
__global__ void k_gather(const int2* __restrict__ es, const int* __restrict__ roff,
                         const float* __restrict__ ete, const float* __restrict__ xW2,
                         const float* __restrict__ q3, const float* __restrict__ p1,
                         const float* __restrict__ p2, const float* __restrict__ xW1,
                         const float* __restrict__ W, float* __restrict__ out) {
  __shared__ float gsh[4][NR];
  int wid = threadIdx.x >> 6;
  int n = blockIdx.x * 4 + wid;  // NN % 4 == 0, grid exact -> no guard
  int l = threadIdx.x & 63;
  int beg = roff[n], end = roff[n + 1];
  float q3l = q3[l];
  float p1n = p1[n];
  float ssum = 0.f, gacc = 0.f, o0 = 0.f, o1 = 0.f;
  for (int jb = beg; jb < end; jb += 64) {
    int m = end - jb;
    if (m > 64) m = 64;
    // padded lanes replay the node's last real edge (cache-hit) with p2=-inf
    int jl = jb + l < end ? jb + l : end - 1;
    int2 ed = es[jl];
    float pv = (jb + l < end) ? p2[ed.y] : -INFINITY;
    for (int jj = 0; jj < m; jj += 16) {
#pragma unroll
      for (int q = 0; q < 16; ++q) {
        // jj+q <= 63 always; overshoot lanes have pv=-inf -> ev=0
        int e_q = __shfl(ed.x, jj + q, 64);
        int d_q = __shfl(ed.y, jj + q, 64);
        float p2q = __shfl(pv, jj + q, 64);
        float tv = __builtin_nontemporal_load(ete + (size_t)e_q * NR + l);
        float2 xv = *(const float2*)(xW2 + (size_t)d_q * OF + 2 * l);
        float ds = tv * q3l;
        ds += __shfl_xor(ds, 1, 64);
        ds += __shfl_xor(ds, 2, 64);
        ds += __shfl_xor(ds, 4, 64);
        ds += __shfl_xor(ds, 8, 64);
        ds += __shfl_xor(ds, 16, 64);
        ds += __shfl_xor(ds, 32, 64);
        float v = p1n + p2q + ds;
        v = v > 0.f ? v : 0.2f * v;
        float evq = __expf(v);
        ssum += evq;
        gacc = fmaf(evq, tv, gacc);
        o0 = fmaf(evq, xv.x, o0);
        o1 = fmaf(evq, xv.y, o1);
      }
    }
  }
  float inv = 1.f / (ssum + 1e-16f);
  float sa = ssum * inv;
  gsh[wid][l] = gacc * inv;
  __syncthreads();
  // epilogue: a = g_row @ W3 for output cols (2l, 2l+1); W3 rows L1-cached
  float a0 = 0.f, a1 = 0.f;
  const float* g_row = gsh[wid];
  for (int d = 0; d < NR; ++d) {
    float gd = g_row[d];  // same address across wave -> LDS broadcast
    float2 w3 = *(const float2*)(W + (size_t)(2 * INF_ + d) * OF + 2 * l);
    a0 = fmaf(gd, w3.x, a0);
    a1 = fmaf(gd, w3.y, a1);
  }
  float2 x1 = *(const float2*)(xW1 + (size_t)n * OF + 2 * l);
  float v0 = fmaf(sa, x1.x, fmaf(o0, inv, a0));
  float v1 = fmaf(sa, x1.y, fmaf(o1, inv, a1));
  v0 = v0 > 0.f ? v0 : expm1f(v0);
  v1 = v1 > 0.f ? v1 : expm1f(v1);
  *(float2*)(out + (size_t)n * OF + 2 * l) = make_float2(v0, v1);
}

extern "C" void kernel_launch(void* const* d_in, const int* in_sizes, int n_in,
                              void* d_out, int out_size, void* d_ws, size_t ws_size,
                              hipStream_t stream) {
  const int* ei = (const int*)d_in[0];
  const float* x = (const float*)d_in[1];
  const float* ete = (const float*)d_in[2];
  const float* W = (const float*)d_in[3];
  const float* a = (const float*)d_in[4];
  float* out = (float*)d_out;

  float* ws = (float*)d_ws;
  float* xW1 = ws;                                  // N*128 (6.4M words)
  float* xW2 = xW1 + (size_t)NN * OF;               // N*128 (6.4M)
  int2* es = (int2*)(xW2 + (size_t)NN * OF);        // E int2 (even word offset)
  float* p1 = (float*)(es + NE);                    // N
  float* p2 = p1 + NN;                              // N
  float* q3 = p2 + NN;                              // 64
  int* cnt = (int*)(q3 + NR);                       // N
  int* roff = cnt + NN;                             // N+1
  int* cur = roff + NN + 1;                         // N
  // total ~14.6M words = 59 MB

  k_init<<<(NN + 255) / 256, 256, 0, stream>>>(W, a, q3, cnt);
  k_node_pre<<<NN / 8, 128, 0, stream>>>(x, W, a, ei, xW1, xW2, p1, p2, cnt);
  k_scan<<<1, SCAN_T, 0, stream>>>(cnt, roff, cur);
  k_scatter<<<NE / 256, 256, 0, stream>>>(ei, cur, es);
  k_gather<<<NN / 4, 256, 0, stream>>>(es, roff, ete, xW2, q3, p1, p2, xW1, W, out);
}

// Round 7
// 809.305 us; speedup vs baseline: 1.3073x; 1.3073x over previous
//
#include <hip/hip_runtime.h>
#include <cmath>

#define NN 50000
#define NE 800000
#define INF_ 128
#define NR 64
#define OF 128
#define SCAN_T 1024

// zero cnt[]; block 0 also computes q3[d] = sum_j W[(256+d),j] * a[j]
__global__ void k_init(const float* __restrict__ W, const float* __restrict__ a,
                       float* __restrict__ q3, int* __restrict__ cnt) {
  int i = blockIdx.x * 256 + threadIdx.x;
  if (i < NN) cnt[i] = 0;
  if (blockIdx.x == 0 && threadIdx.x < NR) {
    const float* row = W + (size_t)(2 * INF_ + threadIdx.x) * OF;
    float acc = 0.f;
    for (int j = 0; j < OF; ++j) acc = fmaf(row[j], a[j], acc);
    q3[threadIdx.x] = acc;
  }
}

// per-node precompute: xW1 = x@W1, xW2 = x@W2, p1 = xW1@a, p2 = xW2@a.
// Fused: src-degree histogram (grid*block == NE exactly, one edge per thread).
__global__ void k_node_pre(const float* __restrict__ x, const float* __restrict__ W,
                           const float* __restrict__ a, const int* __restrict__ ei,
                           float* __restrict__ xW1, float* __restrict__ xW2,
                           float* __restrict__ p1, float* __restrict__ p2,
                           int* __restrict__ cnt) {
  int gid = blockIdx.x * 128 + threadIdx.x;  // 0..799999 == edge id
  atomicAdd(cnt + ei[gid], 1);
  __shared__ float xs[8][INF_];
  __shared__ float red[2][2][8];
  int nb = blockIdx.x * 8;
  int o = threadIdx.x;  // 0..127
  for (int t = 0; t < 8; ++t) xs[t][o] = x[(size_t)(nb + t) * INF_ + o];
  __syncthreads();
  float acc1[8] = {0.f, 0.f, 0.f, 0.f, 0.f, 0.f, 0.f, 0.f};
  float acc2[8] = {0.f, 0.f, 0.f, 0.f, 0.f, 0.f, 0.f, 0.f};
  for (int k = 0; k < INF_; ++k) {
    float w1 = W[(size_t)k * OF + o];
    float w2 = W[(size_t)(INF_ + k) * OF + o];
#pragma unroll
    for (int t = 0; t < 8; ++t) {
      acc1[t] = fmaf(xs[t][k], w1, acc1[t]);
      acc2[t] = fmaf(xs[t][k], w2, acc2[t]);
    }
  }
  float av = a[o];
  int wv = o >> 6, ln = o & 63;
#pragma unroll
  for (int t = 0; t < 8; ++t) {
    xW1[(size_t)(nb + t) * OF + o] = acc1[t];
    xW2[(size_t)(nb + t) * OF + o] = acc2[t];
    float v1 = acc1[t] * av, v2 = acc2[t] * av;
    for (int off = 32; off > 0; off >>= 1) {
      v1 += __shfl_down(v1, off, 64);
      v2 += __shfl_down(v2, off, 64);
    }
    if (ln == 0) { red[0][wv][t] = v1; red[1][wv][t] = v2; }
  }
  __syncthreads();
  if (o < 8) {
    p1[nb + o] = red[0][0][o] + red[0][1][o];
    p2[nb + o] = red[1][0][o] + red[1][1][o];
  }
}

// single-block exclusive scan over cnt -> roff (+cur copy); roff[NN]=NE
__global__ void k_scan(const int* __restrict__ cnt, int* __restrict__ roff,
                       int* __restrict__ cur) {
  __shared__ int part[SCAN_T];
  int t = threadIdx.x;
  const int chunk = (NN + SCAN_T - 1) / SCAN_T;  // 49
  int beg = t * chunk;
  int end = beg + chunk < NN ? beg + chunk : NN;
  int sum = 0;
  for (int i = beg; i < end; ++i) sum += cnt[i];
  part[t] = sum;
  __syncthreads();
  for (int off = 1; off < SCAN_T; off <<= 1) {
    int v = (t >= off) ? part[t - off] : 0;
    __syncthreads();
    part[t] += v;
    __syncthreads();
  }
  int run = (t == 0) ? 0 : part[t - 1];
  for (int i = beg; i < end; ++i) {
    roff[i] = run;
    cur[i] = run;
    run += cnt[i];
  }
  if (t == SCAN_T - 1) roff[NN] = NE;
}

// scatter edge ids + dst into CSR slots (index-only)
__global__ void k_scatter(const int* __restrict__ ei, int* __restrict__ cur,
                          int2* __restrict__ es) {
  int e = blockIdx.x * blockDim.x + threadIdx.x;
  if (e < NE) {
    int pos = atomicAdd(cur + ei[e], 1);
    es[pos] = make_int2(e, ei[NE + e]);
  }
}

// fully fused per-node pass (gather + finalize): one wave per node, single
// read of ete. Inner loop is the proven round-5 structure: unroll 8, plain
// loads (unroll 16 + nontemporal caused register spills -> 975MB of scratch
// writes and a 7x regression). Epilogue: g_row via LDS, g@W3 (L1-resident),
// + sa*xW1 + normalized o, ELU, single out store.
__global__ void k_gather(const int2* __restrict__ es, const int* __restrict__ roff,
                         const float* __restrict__ ete, const float* __restrict__ xW2,
                         const float* __restrict__ q3, const float* __restrict__ p1,
                         const float* __restrict__ p2, const float* __restrict__ xW1,
                         const float* __restrict__ W, float* __restrict__ out) {
  __shared__ float gsh[4][NR];
  int wid = threadIdx.x >> 6;
  int n = blockIdx.x * 4 + wid;  // NN % 4 == 0, grid exact -> no guard
  int l = threadIdx.x & 63;
  int beg = roff[n], end = roff[n + 1];
  float q3l = q3[l];
  float p1n = p1[n];
  float ssum = 0.f, gacc = 0.f, o0 = 0.f, o1 = 0.f;
  for (int jb = beg; jb < end; jb += 64) {
    int m = end - jb;
    if (m > 64) m = 64;
    int2 ed = make_int2(0, 0);
    float pv = -INFINITY;  // padded lanes -> ev = exp(-inf) = 0
    if (jb + l < end) { ed = es[jb + l]; pv = p2[ed.y]; }
    for (int jj = 0; jj < m; jj += 8) {
#pragma unroll
      for (int q = 0; q < 8; ++q) {
        // jj+q <= 63 always; overshoot lanes have pv=-inf and safe (0,0) idx
        int e_q = __shfl(ed.x, jj + q, 64);
        int d_q = __shfl(ed.y, jj + q, 64);
        float p2q = __shfl(pv, jj + q, 64);
        float tv = ete[(size_t)e_q * NR + l];
        float2 xv = *(const float2*)(xW2 + (size_t)d_q * OF + 2 * l);
        float ds = tv * q3l;
        ds += __shfl_xor(ds, 1, 64);
        ds += __shfl_xor(ds, 2, 64);
        ds += __shfl_xor(ds, 4, 64);
        ds += __shfl_xor(ds, 8, 64);
        ds += __shfl_xor(ds, 16, 64);
        ds += __shfl_xor(ds, 32, 64);
        float v = p1n + p2q + ds;
        v = v > 0.f ? v : 0.2f * v;
        float evq = __expf(v);
        ssum += evq;
        gacc = fmaf(evq, tv, gacc);
        o0 = fmaf(evq, xv.x, o0);
        o1 = fmaf(evq, xv.y, o1);
      }
    }
  }
  float inv = 1.f / (ssum + 1e-16f);
  float sa = ssum * inv;
  gsh[wid][l] = gacc * inv;
  __syncthreads();
  // epilogue: a = g_row @ W3 for output cols (2l, 2l+1); W3 rows L1-cached
  float a0 = 0.f, a1 = 0.f;
  const float* g_row = gsh[wid];
  for (int d = 0; d < NR; ++d) {
    float gd = g_row[d];  // same address across wave -> LDS broadcast
    float2 w3 = *(const float2*)(W + (size_t)(2 * INF_ + d) * OF + 2 * l);
    a0 = fmaf(gd, w3.x, a0);
    a1 = fmaf(gd, w3.y, a1);
  }
  float2 x1 = *(const float2*)(xW1 + (size_t)n * OF + 2 * l);
  float v0 = fmaf(sa, x1.x, fmaf(o0, inv, a0));
  float v1 = fmaf(sa, x1.y, fmaf(o1, inv, a1));
  v0 = v0 > 0.f ? v0 : expm1f(v0);
  v1 = v1 > 0.f ? v1 : expm1f(v1);
  *(float2*)(out + (size_t)n * OF + 2 * l) = make_float2(v0, v1);
}

extern "C" void kernel_launch(void* const* d_in, const int* in_sizes, int n_in,
                              void* d_out, int out_size, void* d_ws, size_t ws_size,
                              hipStream_t stream) {
  const int* ei = (const int*)d_in[0];
  const float* x = (const float*)d_in[1];
  const float* ete = (const float*)d_in[2];
  const float* W = (const float*)d_in[3];
  const float* a = (const float*)d_in[4];
  float* out = (float*)d_out;

  float* ws = (float*)d_ws;
  float* xW1 = ws;                                  // N*128 (6.4M words)
  float* xW2 = xW1 + (size_t)NN * OF;               // N*128 (6.4M)
  int2* es = (int2*)(xW2 + (size_t)NN * OF);        // E int2 (even word offset)
  float* p1 = (float*)(es + NE);                    // N
  float* p2 = p1 + NN;                              // N
  float* q3 = p2 + NN;                              // 64
  int* cnt = (int*)(q3 + NR);                       // N
  int* roff = cnt + NN;                             // N+1
  int* cur = roff + NN + 1;                         // N
  // total ~14.6M words = 59 MB

  k_init<<<(NN + 255) / 256, 256, 0, stream>>>(W, a, q3, cnt);
  k_node_pre<<<NN / 8, 128, 0, stream>>>(x, W, a, ei, xW1, xW2, p1, p2, cnt);
  k_scan<<<1, SCAN_T, 0, stream>>>(cnt, roff, cur);
  k_scatter<<<NE / 256, 256, 0, stream>>>(ei, cur, es);
  k_gather<<<NN / 4, 256, 0, stream>>>(es, roff, ete, xW2, q3, p1, p2, xW1, W, out);
}

// Round 8
// 431.403 us; speedup vs baseline: 2.4524x; 1.8760x over previous
//
#include <hip/hip_runtime.h>
#include <cmath>

#define NN 50000
#define NE 800000
#define INF_ 128
#define NR 64
#define OF 128
#define SCAN_T 1024

// zero cnt[]; block 0 also computes q3[d] = sum_j W[(256+d),j] * a[j]
__global__ void k_init(const float* __restrict__ W, const float* __restrict__ a,
                       float* __restrict__ q3, int* __restrict__ cnt) {
  int i = blockIdx.x * 256 + threadIdx.x;
  if (i < NN) cnt[i] = 0;
  if (blockIdx.x == 0 && threadIdx.x < NR) {
    const float* row = W + (size_t)(2 * INF_ + threadIdx.x) * OF;
    float acc = 0.f;
    for (int j = 0; j < OF; ++j) acc = fmaf(row[j], a[j], acc);
    q3[threadIdx.x] = acc;
  }
}

// per-node precompute: xW1 = x@W1, xW2 = x@W2, p1 = xW1@a, p2 = xW2@a.
// Fused: src-degree histogram (grid*block == NE exactly, one edge per thread).
__global__ void k_node_pre(const float* __restrict__ x, const float* __restrict__ W,
                           const float* __restrict__ a, const int* __restrict__ ei,
                           float* __restrict__ xW1, float* __restrict__ xW2,
                           float* __restrict__ p1, float* __restrict__ p2,
                           int* __restrict__ cnt) {
  int gid = blockIdx.x * 128 + threadIdx.x;  // 0..799999 == edge id
  atomicAdd(cnt + ei[gid], 1);
  __shared__ float xs[8][INF_];
  __shared__ float red[2][2][8];
  int nb = blockIdx.x * 8;
  int o = threadIdx.x;  // 0..127
  for (int t = 0; t < 8; ++t) xs[t][o] = x[(size_t)(nb + t) * INF_ + o];
  __syncthreads();
  float acc1[8] = {0.f, 0.f, 0.f, 0.f, 0.f, 0.f, 0.f, 0.f};
  float acc2[8] = {0.f, 0.f, 0.f, 0.f, 0.f, 0.f, 0.f, 0.f};
  for (int k = 0; k < INF_; ++k) {
    float w1 = W[(size_t)k * OF + o];
    float w2 = W[(size_t)(INF_ + k) * OF + o];
#pragma unroll
    for (int t = 0; t < 8; ++t) {
      acc1[t] = fmaf(xs[t][k], w1, acc1[t]);
      acc2[t] = fmaf(xs[t][k], w2, acc2[t]);
    }
  }
  float av = a[o];
  int wv = o >> 6, ln = o & 63;
#pragma unroll
  for (int t = 0; t < 8; ++t) {
    xW1[(size_t)(nb + t) * OF + o] = acc1[t];
    xW2[(size_t)(nb + t) * OF + o] = acc2[t];
    float v1 = acc1[t] * av, v2 = acc2[t] * av;
    for (int off = 32; off > 0; off >>= 1) {
      v1 += __shfl_down(v1, off, 64);
      v2 += __shfl_down(v2, off, 64);
    }
    if (ln == 0) { red[0][wv][t] = v1; red[1][wv][t] = v2; }
  }
  __syncthreads();
  if (o < 8) {
    p1[nb + o] = red[0][0][o] + red[0][1][o];
    p2[nb + o] = red[1][0][o] + red[1][1][o];
  }
}

// single-block exclusive scan over cnt -> roff (+cur copy); roff[NN]=NE
__global__ void k_scan(const int* __restrict__ cnt, int* __restrict__ roff,
                       int* __restrict__ cur) {
  __shared__ int part[SCAN_T];
  int t = threadIdx.x;
  const int chunk = (NN + SCAN_T - 1) / SCAN_T;  // 49
  int beg = t * chunk;
  int end = beg + chunk < NN ? beg + chunk : NN;
  int sum = 0;
  for (int i = beg; i < end; ++i) sum += cnt[i];
  part[t] = sum;
  __syncthreads();
  for (int off = 1; off < SCAN_T; off <<= 1) {
    int v = (t >= off) ? part[t - off] : 0;
    __syncthreads();
    part[t] += v;
    __syncthreads();
  }
  int run = (t == 0) ? 0 : part[t - 1];
  for (int i = beg; i < end; ++i) {
    roff[i] = run;
    cur[i] = run;
    run += cnt[i];
  }
  if (t == SCAN_T - 1) roff[NN] = NE;
}

// scatter edge ids + dst into CSR slots (index-only)
__global__ void k_scatter(const int* __restrict__ ei, int* __restrict__ cur,
                          int2* __restrict__ es) {
  int e = blockIdx.x * blockDim.x + threadIdx.x;
  if (e < NE) {
    int pos = atomicAdd(cur + ei[e], 1);
    es[pos] = make_int2(e, ei[NE + e]);
  }
}

// fully fused per-node pass (gather + finalize): one wave per node, single
// read of ete. Inner loop: round-5 structure (unroll 8, plain loads).
// Epilogue d-loop is pinned to unroll 4 — with full unroll (64, compile-time
// bound) the compiler hoisted ~64 float2 W3 loads, capped at VGPR=64 and
// spilled ~975MB/dispatch of scratch; traffic was per-NODE (epilogue), which
// is why reverting only the inner loop (round 7) didn't remove it.
__global__ void k_gather(const int2* __restrict__ es, const int* __restrict__ roff,
                         const float* __restrict__ ete, const float* __restrict__ xW2,
                         const float* __restrict__ q3, const float* __restrict__ p1,
                         const float* __restrict__ p2, const float* __restrict__ xW1,
                         const float* __restrict__ W, float* __restrict__ out) {
  __shared__ float gsh[4][NR];
  int wid = threadIdx.x >> 6;
  int n = blockIdx.x * 4 + wid;  // NN % 4 == 0, grid exact -> no guard
  int l = threadIdx.x & 63;
  int beg = roff[n], end = roff[n + 1];
  float q3l = q3[l];
  float p1n = p1[n];
  float ssum = 0.f, gacc = 0.f, o0 = 0.f, o1 = 0.f;
  for (int jb = beg; jb < end; jb += 64) {
    int m = end - jb;
    if (m > 64) m = 64;
    int2 ed = make_int2(0, 0);
    float pv = -INFINITY;  // padded lanes -> ev = exp(-inf) = 0
    if (jb + l < end) { ed = es[jb + l]; pv = p2[ed.y]; }
    for (int jj = 0; jj < m; jj += 8) {
#pragma unroll
      for (int q = 0; q < 8; ++q) {
        // jj+q <= 63 always; overshoot lanes have pv=-inf and safe (0,0) idx
        int e_q = __shfl(ed.x, jj + q, 64);
        int d_q = __shfl(ed.y, jj + q, 64);
        float p2q = __shfl(pv, jj + q, 64);
        float tv = ete[(size_t)e_q * NR + l];
        float2 xv = *(const float2*)(xW2 + (size_t)d_q * OF + 2 * l);
        float ds = tv * q3l;
        ds += __shfl_xor(ds, 1, 64);
        ds += __shfl_xor(ds, 2, 64);
        ds += __shfl_xor(ds, 4, 64);
        ds += __shfl_xor(ds, 8, 64);
        ds += __shfl_xor(ds, 16, 64);
        ds += __shfl_xor(ds, 32, 64);
        float v = p1n + p2q + ds;
        v = v > 0.f ? v : 0.2f * v;
        float evq = __expf(v);
        ssum += evq;
        gacc = fmaf(evq, tv, gacc);
        o0 = fmaf(evq, xv.x, o0);
        o1 = fmaf(evq, xv.y, o1);
      }
    }
  }
  float inv = 1.f / (ssum + 1e-16f);
  float sa = ssum * inv;
  gsh[wid][l] = gacc * inv;
  __syncthreads();
  // epilogue: a = g_row @ W3 for output cols (2l, 2l+1); W3 rows L2-cached.
  // unroll 4 keeps ~12 regs live (full unroll spilled — see kernel comment).
  float a0 = 0.f, a1 = 0.f;
  const float* g_row = gsh[wid];
#pragma unroll 4
  for (int d = 0; d < NR; ++d) {
    float gd = g_row[d];  // same address across wave -> LDS broadcast
    float2 w3 = *(const float2*)(W + (size_t)(2 * INF_ + d) * OF + 2 * l);
    a0 = fmaf(gd, w3.x, a0);
    a1 = fmaf(gd, w3.y, a1);
  }
  float2 x1 = *(const float2*)(xW1 + (size_t)n * OF + 2 * l);
  float v0 = fmaf(sa, x1.x, fmaf(o0, inv, a0));
  float v1 = fmaf(sa, x1.y, fmaf(o1, inv, a1));
  v0 = v0 > 0.f ? v0 : expm1f(v0);
  v1 = v1 > 0.f ? v1 : expm1f(v1);
  *(float2*)(out + (size_t)n * OF + 2 * l) = make_float2(v0, v1);
}

extern "C" void kernel_launch(void* const* d_in, const int* in_sizes, int n_in,
                              void* d_out, int out_size, void* d_ws, size_t ws_size,
                              hipStream_t stream) {
  const int* ei = (const int*)d_in[0];
  const float* x = (const float*)d_in[1];
  const float* ete = (const float*)d_in[2];
  const float* W = (const float*)d_in[3];
  const float* a = (const float*)d_in[4];
  float* out = (float*)d_out;

  float* ws = (float*)d_ws;
  float* xW1 = ws;                                  // N*128 (6.4M words)
  float* xW2 = xW1 + (size_t)NN * OF;               // N*128 (6.4M)
  int2* es = (int2*)(xW2 + (size_t)NN * OF);        // E int2 (even word offset)
  float* p1 = (float*)(es + NE);                    // N
  float* p2 = p1 + NN;                              // N
  float* q3 = p2 + NN;                              // 64
  int* cnt = (int*)(q3 + NR);                       // N
  int* roff = cnt + NN;                             // N+1
  int* cur = roff + NN + 1;                         // N
  // total ~14.6M words = 59 MB

  k_init<<<(NN + 255) / 256, 256, 0, stream>>>(W, a, q3, cnt);
  k_node_pre<<<NN / 8, 128, 0, stream>>>(x, W, a, ei, xW1, xW2, p1, p2, cnt);
  k_scan<<<1, SCAN_T, 0, stream>>>(cnt, roff, cur);
  k_scatter<<<NE / 256, 256, 0, stream>>>(ei, cur, es);
  k_gather<<<NN / 4, 256, 0, stream>>>(es, roff, ete, xW2, q3, p1, p2, xW1, W, out);
}

// Round 9
// 383.380 us; speedup vs baseline: 2.7596x; 1.1253x over previous
//
#include <hip/hip_runtime.h>
#include <cmath>

#define NN 50000
#define NE 800000
#define INF_ 128
#define NR 64
#define OF 128
#define SCAN_T 1024

// zero cnt[]; block 0 also computes q3[d] = sum_j W[(256+d),j] * a[j]
__global__ void k_init(const float* __restrict__ W, const float* __restrict__ a,
                       float* __restrict__ q3, int* __restrict__ cnt) {
  int i = blockIdx.x * 256 + threadIdx.x;
  if (i < NN) cnt[i] = 0;
  if (blockIdx.x == 0 && threadIdx.x < NR) {
    const float* row = W + (size_t)(2 * INF_ + threadIdx.x) * OF;
    float acc = 0.f;
    for (int j = 0; j < OF; ++j) acc = fmaf(row[j], a[j], acc);
    q3[threadIdx.x] = acc;
  }
}

// per-node precompute: xW1 = x@W1, xW2 = x@W2, p1 = xW1@a, p2 = xW2@a.
// Fused: src-degree histogram (grid*block == NE exactly, one edge per thread).
__global__ void k_node_pre(const float* __restrict__ x, const float* __restrict__ W,
                           const float* __restrict__ a, const int* __restrict__ ei,
                           float* __restrict__ xW1, float* __restrict__ xW2,
                           float* __restrict__ p1, float* __restrict__ p2,
                           int* __restrict__ cnt) {
  int gid = blockIdx.x * 128 + threadIdx.x;  // 0..799999 == edge id
  atomicAdd(cnt + ei[gid], 1);
  __shared__ float xs[8][INF_];
  __shared__ float red[2][2][8];
  int nb = blockIdx.x * 8;
  int o = threadIdx.x;  // 0..127
  for (int t = 0; t < 8; ++t) xs[t][o] = x[(size_t)(nb + t) * INF_ + o];
  __syncthreads();
  float acc1[8] = {0.f, 0.f, 0.f, 0.f, 0.f, 0.f, 0.f, 0.f};
  float acc2[8] = {0.f, 0.f, 0.f, 0.f, 0.f, 0.f, 0.f, 0.f};
  for (int k = 0; k < INF_; ++k) {
    float w1 = W[(size_t)k * OF + o];
    float w2 = W[(size_t)(INF_ + k) * OF + o];
#pragma unroll
    for (int t = 0; t < 8; ++t) {
      acc1[t] = fmaf(xs[t][k], w1, acc1[t]);
      acc2[t] = fmaf(xs[t][k], w2, acc2[t]);
    }
  }
  float av = a[o];
  int wv = o >> 6, ln = o & 63;
#pragma unroll
  for (int t = 0; t < 8; ++t) {
    xW1[(size_t)(nb + t) * OF + o] = acc1[t];
    xW2[(size_t)(nb + t) * OF + o] = acc2[t];
    float v1 = acc1[t] * av, v2 = acc2[t] * av;
    for (int off = 32; off > 0; off >>= 1) {
      v1 += __shfl_down(v1, off, 64);
      v2 += __shfl_down(v2, off, 64);
    }
    if (ln == 0) { red[0][wv][t] = v1; red[1][wv][t] = v2; }
  }
  __syncthreads();
  if (o < 8) {
    p1[nb + o] = red[0][0][o] + red[0][1][o];
    p2[nb + o] = red[1][0][o] + red[1][1][o];
  }
}

// single-block exclusive scan over cnt -> roff (+cur copy); roff[NN]=NE
__global__ void k_scan(const int* __restrict__ cnt, int* __restrict__ roff,
                       int* __restrict__ cur) {
  __shared__ int part[SCAN_T];
  int t = threadIdx.x;
  const int chunk = (NN + SCAN_T - 1) / SCAN_T;  // 49
  int beg = t * chunk;
  int end = beg + chunk < NN ? beg + chunk : NN;
  int sum = 0;
  for (int i = beg; i < end; ++i) sum += cnt[i];
  part[t] = sum;
  __syncthreads();
  for (int off = 1; off < SCAN_T; off <<= 1) {
    int v = (t >= off) ? part[t - off] : 0;
    __syncthreads();
    part[t] += v;
    __syncthreads();
  }
  int run = (t == 0) ? 0 : part[t - 1];
  for (int i = beg; i < end; ++i) {
    roff[i] = run;
    cur[i] = run;
    run += cnt[i];
  }
  if (t == SCAN_T - 1) roff[NN] = NE;
}

// scatter (edge id, dst) + p2[dst] into CSR slots. The p2 gather lives here
// (800K-thread parallelism hides the random 4B reads) so k_gather's chunk
// prologue is purely coalesced streaming loads.
__global__ void k_scatter(const int* __restrict__ ei, const float* __restrict__ p2,
                          int* __restrict__ cur, int2* __restrict__ es,
                          float* __restrict__ wpv) {
  int e = blockIdx.x * blockDim.x + threadIdx.x;
  if (e < NE) {
    int dst = ei[NE + e];
    int pos = atomicAdd(cur + ei[e], 1);
    es[pos] = make_int2(e, dst);
    wpv[pos] = p2[dst];
  }
}

// per-node gather: TWO nodes per wave (independent edge streams -> 2x MLP).
// No LDS, no barrier (round-8 lesson: __syncthreads coupling waves of
// different-degree nodes cost ~35% block residency). Per edge: logit =
// p1[n]+pv+ete[e]·q3 (64-lane butterfly), ev=exp(leaky_relu); accumulate
// ssum, ev*ete, ev*xW2[dst] unnormalized; normalize at the end. Masked
// lanes carry pv=-inf -> ev=0 (mask travels with the broadcast lane).
__global__ void k_gather(const int2* __restrict__ es, const float* __restrict__ wpv,
                         const int* __restrict__ roff,
                         const float* __restrict__ ete, const float* __restrict__ xW2,
                         const float* __restrict__ q3, const float* __restrict__ p1,
                         float* __restrict__ g, float* __restrict__ out,
                         float* __restrict__ s) {
  int wv = blockIdx.x * 4 + (threadIdx.x >> 6);  // wave id; grid exact
  int nA = wv * 2, nB = nA + 1;
  int l = threadIdx.x & 63;
  float q3l = q3[l];
  int begA = roff[nA], endA = roff[nA + 1], endB = roff[nB + 1];
  float p1A = p1[nA], p1B = p1[nB];
  float ssA = 0.f, gaA = 0.f, oA0 = 0.f, oA1 = 0.f;
  float ssB = 0.f, gaB = 0.f, oB0 = 0.f, oB1 = 0.f;
  int jbA = begA, jbB = endA;  // begB == endA (CSR contiguity)
  while (jbA < endA || jbB < endB) {
    int2 edA = make_int2(0, 0), edB = make_int2(0, 0);
    float pvA = -INFINITY, pvB = -INFINITY;
    if (jbA + l < endA) { edA = es[jbA + l]; pvA = wpv[jbA + l]; }
    if (jbB + l < endB) { edB = es[jbB + l]; pvB = wpv[jbB + l]; }
    int mA = endA - jbA; mA = mA < 0 ? 0 : (mA > 64 ? 64 : mA);
    int mB = endB - jbB; mB = mB < 0 ? 0 : (mB > 64 ? 64 : mB);
    int mm = mA > mB ? mA : mB;
    for (int jj = 0; jj < mm; jj += 4) {
#pragma unroll
      for (int q = 0; q < 4; ++q) {
        // jj+q <= 63 always; lanes beyond a node's m hold pv=-inf -> ev=0
        int eA = __shfl(edA.x, jj + q, 64);
        int dA = __shfl(edA.y, jj + q, 64);
        float pA = __shfl(pvA, jj + q, 64);
        int eB = __shfl(edB.x, jj + q, 64);
        int dB = __shfl(edB.y, jj + q, 64);
        float pB = __shfl(pvB, jj + q, 64);
        float tA = ete[(size_t)eA * NR + l];
        float tB = ete[(size_t)eB * NR + l];
        float2 xA = *(const float2*)(xW2 + (size_t)dA * OF + 2 * l);
        float2 xB = *(const float2*)(xW2 + (size_t)dB * OF + 2 * l);
        float dsA = tA * q3l, dsB = tB * q3l;
        dsA += __shfl_xor(dsA, 1, 64);  dsB += __shfl_xor(dsB, 1, 64);
        dsA += __shfl_xor(dsA, 2, 64);  dsB += __shfl_xor(dsB, 2, 64);
        dsA += __shfl_xor(dsA, 4, 64);  dsB += __shfl_xor(dsB, 4, 64);
        dsA += __shfl_xor(dsA, 8, 64);  dsB += __shfl_xor(dsB, 8, 64);
        dsA += __shfl_xor(dsA, 16, 64); dsB += __shfl_xor(dsB, 16, 64);
        dsA += __shfl_xor(dsA, 32, 64); dsB += __shfl_xor(dsB, 32, 64);
        float vA = p1A + pA + dsA;
        float vB = p1B + pB + dsB;
        vA = vA > 0.f ? vA : 0.2f * vA;
        vB = vB > 0.f ? vB : 0.2f * vB;
        float eVA = __expf(vA);
        float eVB = __expf(vB);
        ssA += eVA;               ssB += eVB;
        gaA = fmaf(eVA, tA, gaA); gaB = fmaf(eVB, tB, gaB);
        oA0 = fmaf(eVA, xA.x, oA0); oB0 = fmaf(eVB, xB.x, oB0);
        oA1 = fmaf(eVA, xA.y, oA1); oB1 = fmaf(eVB, xB.y, oB1);
      }
    }
    jbA += 64; jbB += 64;
  }
  float invA = 1.f / (ssA + 1e-16f);
  float invB = 1.f / (ssB + 1e-16f);
  g[(size_t)nA * NR + l] = gaA * invA;
  g[(size_t)nB * NR + l] = gaB * invB;
  *(float2*)(out + (size_t)nA * OF + 2 * l) = make_float2(oA0 * invA, oA1 * invA);
  *(float2*)(out + (size_t)nB * OF + 2 * l) = make_float2(oB0 * invB, oB1 * invB);
  if (l == 0) { s[nA] = ssA; s[nB] = ssB; }
}

// finalize: out = elu( (s/(s+1e-16))*xW1 + out + g@W3 ), 8 nodes/block.
// Separate kernel (not fused into gather): W3 amortized over 8 nodes, and
// gather waves never barrier-couple across node degrees.
__global__ void k_final(const float* __restrict__ xW1, const float* __restrict__ g,
                        const float* __restrict__ s, const float* __restrict__ W,
                        float* __restrict__ out) {
  __shared__ float gs[8 * NR];
  int nb = blockIdx.x * 8;
  int o = threadIdx.x;  // 0..127
  for (int i = o; i < 8 * NR; i += 128) gs[i] = g[(size_t)nb * NR + i];
  __syncthreads();
  float acc[8] = {0.f, 0.f, 0.f, 0.f, 0.f, 0.f, 0.f, 0.f};
  for (int d = 0; d < NR; ++d) {
    float w3 = W[(size_t)(2 * INF_ + d) * OF + o];
#pragma unroll
    for (int t = 0; t < 8; ++t) acc[t] = fmaf(gs[t * NR + d], w3, acc[t]);
  }
#pragma unroll
  for (int t = 0; t < 8; ++t) {
    int n = nb + t;
    float sv = s[n];
    float sa = sv > 0.f ? sv / (sv + 1e-16f) : 0.f;
    float v = sa * xW1[(size_t)n * OF + o] + out[(size_t)n * OF + o] + acc[t];
    out[(size_t)n * OF + o] = v > 0.f ? v : expm1f(v);
  }
}

extern "C" void kernel_launch(void* const* d_in, const int* in_sizes, int n_in,
                              void* d_out, int out_size, void* d_ws, size_t ws_size,
                              hipStream_t stream) {
  const int* ei = (const int*)d_in[0];
  const float* x = (const float*)d_in[1];
  const float* ete = (const float*)d_in[2];
  const float* W = (const float*)d_in[3];
  const float* a = (const float*)d_in[4];
  float* out = (float*)d_out;

  float* ws = (float*)d_ws;
  float* xW1 = ws;                                  // N*128 (6.4M words)
  float* xW2 = xW1 + (size_t)NN * OF;               // N*128 (6.4M)
  int2* es = (int2*)(xW2 + (size_t)NN * OF);        // E int2 (even word offset)
  float* wpv = (float*)(es + NE);                   // E
  float* g = wpv + NE;                              // N*64 (3.2M)
  float* p1 = g + (size_t)NN * NR;                  // N
  float* p2 = p1 + NN;                              // N
  float* q3 = p2 + NN;                              // 64
  int* cnt = (int*)(q3 + NR);                       // N
  int* roff = cnt + NN;                             // N+1
  int* cur = roff + NN + 1;                         // N
  float* s = (float*)(cur + NN);                    // N
  // total ~19.3M words = 78 MB

  k_init<<<(NN + 255) / 256, 256, 0, stream>>>(W, a, q3, cnt);
  k_node_pre<<<NN / 8, 128, 0, stream>>>(x, W, a, ei, xW1, xW2, p1, p2, cnt);
  k_scan<<<1, SCAN_T, 0, stream>>>(cnt, roff, cur);
  k_scatter<<<NE / 256, 256, 0, stream>>>(ei, p2, cur, es, wpv);
  k_gather<<<NN / 8, 256, 0, stream>>>(es, wpv, roff, ete, xW2, q3, p1, g, out, s);
  k_final<<<NN / 8, 128, 0, stream>>>(xW1, g, s, W, out);
}

// Round 10
// 281.472 us; speedup vs baseline: 3.7587x; 1.3621x over previous
//
#include <hip/hip_runtime.h>
#include <cmath>

#define NN 50000
#define NE 800000
#define INF_ 128
#define NR 64
#define OF 128
#define TS 256
#define NT ((NN + TS - 1) / TS)  // 196 tiles

__device__ __forceinline__ unsigned short f2bf_rne(float f) {
  unsigned u = __float_as_uint(f);
  u += 0x7FFFu + ((u >> 16) & 1u);  // round-to-nearest-even
  return (unsigned short)(u >> 16);
}

// zero cnt[]; block 0 also computes q3[d] = sum_j W[(256+d),j] * a[j]
__global__ void k_init(const float* __restrict__ W, const float* __restrict__ a,
                       float* __restrict__ q3, int* __restrict__ cnt) {
  int i = blockIdx.x * 256 + threadIdx.x;
  if (i < NN) cnt[i] = 0;
  if (blockIdx.x == 0 && threadIdx.x < NR) {
    const float* row = W + (size_t)(2 * INF_ + threadIdx.x) * OF;
    float acc = 0.f;
    for (int j = 0; j < OF; ++j) acc = fmaf(row[j], a[j], acc);
    q3[threadIdx.x] = acc;
  }
}

// per-node precompute: xW1 = x@W1 (fp32), xw2h = x@W2 (bf16), p1, p2.
// Fused: src-degree histogram (grid*block == NE exactly, one edge per thread).
__global__ void k_node_pre(const float* __restrict__ x, const float* __restrict__ W,
                           const float* __restrict__ a, const int* __restrict__ ei,
                           float* __restrict__ xW1, unsigned short* __restrict__ xw2h,
                           float* __restrict__ p1, float* __restrict__ p2,
                           int* __restrict__ cnt) {
  int gid = blockIdx.x * 128 + threadIdx.x;  // 0..799999 == edge id
  atomicAdd(cnt + ei[gid], 1);
  __shared__ float xs[8][INF_];
  __shared__ float red[2][2][8];
  int nb = blockIdx.x * 8;
  int o = threadIdx.x;  // 0..127
  for (int t = 0; t < 8; ++t) xs[t][o] = x[(size_t)(nb + t) * INF_ + o];
  __syncthreads();
  float acc1[8] = {0.f, 0.f, 0.f, 0.f, 0.f, 0.f, 0.f, 0.f};
  float acc2[8] = {0.f, 0.f, 0.f, 0.f, 0.f, 0.f, 0.f, 0.f};
  for (int k = 0; k < INF_; ++k) {
    float w1 = W[(size_t)k * OF + o];
    float w2 = W[(size_t)(INF_ + k) * OF + o];
#pragma unroll
    for (int t = 0; t < 8; ++t) {
      acc1[t] = fmaf(xs[t][k], w1, acc1[t]);
      acc2[t] = fmaf(xs[t][k], w2, acc2[t]);
    }
  }
  float av = a[o];
  int wv = o >> 6, ln = o & 63;
#pragma unroll
  for (int t = 0; t < 8; ++t) {
    xW1[(size_t)(nb + t) * OF + o] = acc1[t];
    xw2h[(size_t)(nb + t) * OF + o] = f2bf_rne(acc2[t]);
    float v1 = acc1[t] * av, v2 = acc2[t] * av;
    for (int off = 32; off > 0; off >>= 1) {
      v1 += __shfl_down(v1, off, 64);
      v2 += __shfl_down(v2, off, 64);
    }
    if (ln == 0) { red[0][wv][t] = v1; red[1][wv][t] = v2; }
  }
  __syncthreads();
  if (o < 8) {
    p1[nb + o] = red[0][0][o] + red[0][1][o];
    p2[nb + o] = red[1][0][o] + red[1][1][o];
  }
}

// hierarchical scan, phase A: coalesced per-tile exclusive scan + tile sums
// (replaces the single-block scan: 1024 threads x 49-elem strided chunks was
// uncoalesced and single-CU, ~25us)
__global__ void k_scanA(const int* __restrict__ cnt, int* __restrict__ roff,
                        int* __restrict__ tsum) {
  __shared__ int sh[TS];
  int b = blockIdx.x, t = threadIdx.x;
  int i = b * TS + t;
  int v = (i < NN) ? cnt[i] : 0;
  sh[t] = v;
  __syncthreads();
  for (int off = 1; off < TS; off <<= 1) {
    int u = (t >= off) ? sh[t - off] : 0;
    __syncthreads();
    sh[t] += u;
    __syncthreads();
  }
  if (i < NN) roff[i] = sh[t] - v;  // exclusive within tile
  if (t == TS - 1) tsum[b] = sh[t];
}

// phase B: every block redundantly LDS-scans the 196 tile sums, adds its
// tile offset, and writes roff (+cur copy); last block sets roff[NN]=NE.
__global__ void k_scanB(const int* __restrict__ tsum, int* __restrict__ roff,
                        int* __restrict__ cur) {
  __shared__ int sh[256];
  int b = blockIdx.x, t = threadIdx.x;
  sh[t] = (t < NT) ? tsum[t] : 0;
  __syncthreads();
  for (int off = 1; off < 256; off <<= 1) {
    int u = (t >= off) ? sh[t - off] : 0;
    __syncthreads();
    sh[t] += u;
    __syncthreads();
  }
  int toff = (b == 0) ? 0 : sh[b - 1];
  int i = b * TS + t;
  if (i < NN) {
    int r = roff[i] + toff;
    roff[i] = r;
    cur[i] = r;
  }
  if (b == NT - 1 && t == 0) roff[NN] = NE;
}

// scatter (edge id, dst) + p2[dst] into CSR slots. The p2 gather lives here
// (800K-thread parallelism hides the random 4B reads).
__global__ void k_scatter(const int* __restrict__ ei, const float* __restrict__ p2,
                          int* __restrict__ cur, int2* __restrict__ es,
                          float* __restrict__ wpv) {
  int e = blockIdx.x * blockDim.x + threadIdx.x;
  if (e < NE) {
    int dst = ei[NE + e];
    int pos = atomicAdd(cur + ei[e], 1);
    es[pos] = make_int2(e, dst);
    wpv[pos] = p2[dst];
  }
}

// per-node gather: TWO nodes per wave (independent edge streams). No LDS,
// no barrier. xW2 is read as bf16 (4B/lane -> 2 cache lines/edge instead of
// 4; bf16 rel err ~0.2% on a ~0.6-magnitude term, well inside threshold).
__global__ void k_gather(const int2* __restrict__ es, const float* __restrict__ wpv,
                         const int* __restrict__ roff,
                         const float* __restrict__ ete,
                         const unsigned short* __restrict__ xw2h,
                         const float* __restrict__ q3, const float* __restrict__ p1,
                         float* __restrict__ g, float* __restrict__ out,
                         float* __restrict__ s) {
  int wv = blockIdx.x * 4 + (threadIdx.x >> 6);  // wave id; grid exact
  int nA = wv * 2, nB = nA + 1;
  int l = threadIdx.x & 63;
  float q3l = q3[l];
  int begA = roff[nA], endA = roff[nA + 1], endB = roff[nB + 1];
  float p1A = p1[nA], p1B = p1[nB];
  float ssA = 0.f, gaA = 0.f, oA0 = 0.f, oA1 = 0.f;
  float ssB = 0.f, gaB = 0.f, oB0 = 0.f, oB1 = 0.f;
  int jbA = begA, jbB = endA;  // begB == endA (CSR contiguity)
  while (jbA < endA || jbB < endB) {
    int2 edA = make_int2(0, 0), edB = make_int2(0, 0);
    float pvA = -INFINITY, pvB = -INFINITY;
    if (jbA + l < endA) { edA = es[jbA + l]; pvA = wpv[jbA + l]; }
    if (jbB + l < endB) { edB = es[jbB + l]; pvB = wpv[jbB + l]; }
    int mA = endA - jbA; mA = mA < 0 ? 0 : (mA > 64 ? 64 : mA);
    int mB = endB - jbB; mB = mB < 0 ? 0 : (mB > 64 ? 64 : mB);
    int mm = mA > mB ? mA : mB;
    for (int jj = 0; jj < mm; jj += 4) {
#pragma unroll
      for (int q = 0; q < 4; ++q) {
        // jj+q <= 63 always; lanes beyond a node's m hold pv=-inf -> ev=0
        int eA = __shfl(edA.x, jj + q, 64);
        int dA = __shfl(edA.y, jj + q, 64);
        float pA = __shfl(pvA, jj + q, 64);
        int eB = __shfl(edB.x, jj + q, 64);
        int dB = __shfl(edB.y, jj + q, 64);
        float pB = __shfl(pvB, jj + q, 64);
        float tA = ete[(size_t)eA * NR + l];
        float tB = ete[(size_t)eB * NR + l];
        unsigned uA = *(const unsigned*)(xw2h + (size_t)dA * OF + 2 * l);
        unsigned uB = *(const unsigned*)(xw2h + (size_t)dB * OF + 2 * l);
        float xA0 = __uint_as_float(uA << 16);
        float xA1 = __uint_as_float(uA & 0xFFFF0000u);
        float xB0 = __uint_as_float(uB << 16);
        float xB1 = __uint_as_float(uB & 0xFFFF0000u);
        float dsA = tA * q3l, dsB = tB * q3l;
        dsA += __shfl_xor(dsA, 1, 64);  dsB += __shfl_xor(dsB, 1, 64);
        dsA += __shfl_xor(dsA, 2, 64);  dsB += __shfl_xor(dsB, 2, 64);
        dsA += __shfl_xor(dsA, 4, 64);  dsB += __shfl_xor(dsB, 4, 64);
        dsA += __shfl_xor(dsA, 8, 64);  dsB += __shfl_xor(dsB, 8, 64);
        dsA += __shfl_xor(dsA, 16, 64); dsB += __shfl_xor(dsB, 16, 64);
        dsA += __shfl_xor(dsA, 32, 64); dsB += __shfl_xor(dsB, 32, 64);
        float vA = p1A + pA + dsA;
        float vB = p1B + pB + dsB;
        vA = vA > 0.f ? vA : 0.2f * vA;
        vB = vB > 0.f ? vB : 0.2f * vB;
        float eVA = __expf(vA);
        float eVB = __expf(vB);
        ssA += eVA;               ssB += eVB;
        gaA = fmaf(eVA, tA, gaA); gaB = fmaf(eVB, tB, gaB);
        oA0 = fmaf(eVA, xA0, oA0); oB0 = fmaf(eVB, xB0, oB0);
        oA1 = fmaf(eVA, xA1, oA1); oB1 = fmaf(eVB, xB1, oB1);
      }
    }
    jbA += 64; jbB += 64;
  }
  float invA = 1.f / (ssA + 1e-16f);
  float invB = 1.f / (ssB + 1e-16f);
  g[(size_t)nA * NR + l] = gaA * invA;
  g[(size_t)nB * NR + l] = gaB * invB;
  *(float2*)(out + (size_t)nA * OF + 2 * l) = make_float2(oA0 * invA, oA1 * invA);
  *(float2*)(out + (size_t)nB * OF + 2 * l) = make_float2(oB0 * invB, oB1 * invB);
  if (l == 0) { s[nA] = ssA; s[nB] = ssB; }
}

// finalize: out = elu( (s/(s+1e-16))*xW1 + out + g@W3 ), 8 nodes/block.
__global__ void k_final(const float* __restrict__ xW1, const float* __restrict__ g,
                        const float* __restrict__ s, const float* __restrict__ W,
                        float* __restrict__ out) {
  __shared__ float gs[8 * NR];
  int nb = blockIdx.x * 8;
  int o = threadIdx.x;  // 0..127
  for (int i = o; i < 8 * NR; i += 128) gs[i] = g[(size_t)nb * NR + i];
  __syncthreads();
  float acc[8] = {0.f, 0.f, 0.f, 0.f, 0.f, 0.f, 0.f, 0.f};
  for (int d = 0; d < NR; ++d) {
    float w3 = W[(size_t)(2 * INF_ + d) * OF + o];
#pragma unroll
    for (int t = 0; t < 8; ++t) acc[t] = fmaf(gs[t * NR + d], w3, acc[t]);
  }
#pragma unroll
  for (int t = 0; t < 8; ++t) {
    int n = nb + t;
    float sv = s[n];
    float sa = sv > 0.f ? sv / (sv + 1e-16f) : 0.f;
    float v = sa * xW1[(size_t)n * OF + o] + out[(size_t)n * OF + o] + acc[t];
    out[(size_t)n * OF + o] = v > 0.f ? v : expm1f(v);
  }
}

extern "C" void kernel_launch(void* const* d_in, const int* in_sizes, int n_in,
                              void* d_out, int out_size, void* d_ws, size_t ws_size,
                              hipStream_t stream) {
  const int* ei = (const int*)d_in[0];
  const float* x = (const float*)d_in[1];
  const float* ete = (const float*)d_in[2];
  const float* W = (const float*)d_in[3];
  const float* a = (const float*)d_in[4];
  float* out = (float*)d_out;

  float* ws = (float*)d_ws;
  float* xW1 = ws;                                      // N*128 fp32 (6.4M words)
  unsigned short* xw2h = (unsigned short*)(xW1 + (size_t)NN * OF);  // N*128 bf16 (3.2M words)
  int2* es = (int2*)(xW1 + (size_t)NN * OF + (size_t)NN * OF / 2);  // E int2 (word off 9.6M, even)
  float* wpv = (float*)(es + NE);                       // E
  float* g = wpv + NE;                                  // N*64
  float* p1 = g + (size_t)NN * NR;                      // N
  float* p2 = p1 + NN;                                  // N
  float* q3 = p2 + NN;                                  // 64
  int* cnt = (int*)(q3 + NR);                           // N
  int* roff = cnt + NN;                                 // N+1
  int* cur = roff + NN + 1;                             // N
  int* tsum = cur + NN;                                 // 256
  float* s = (float*)(tsum + 256);                      // N
  // total ~16.2M words = 65 MB

  k_init<<<(NN + 255) / 256, 256, 0, stream>>>(W, a, q3, cnt);
  k_node_pre<<<NN / 8, 128, 0, stream>>>(x, W, a, ei, xW1, xw2h, p1, p2, cnt);
  k_scanA<<<NT, TS, 0, stream>>>(cnt, roff, tsum);
  k_scanB<<<NT, 256, 0, stream>>>(tsum, roff, cur);
  k_scatter<<<NE / 256, 256, 0, stream>>>(ei, p2, cur, es, wpv);
  k_gather<<<NN / 8, 256, 0, stream>>>(es, wpv, roff, ete, xw2h, q3, p1, g, out, s);
  k_final<<<NN / 8, 128, 0, stream>>>(xW1, g, s, W, out);
}